// Round 1
// baseline (1997.193 us; speedup 1.0000x reference)
//
#include <hip/hip_runtime.h>
#include <cstdint>
#include <cstddef>

#define D_HEAD   64
#define NHEAD    16
#define DMODEL   1024
#define SLEN     2048
#define BSZ      4
#define MROWS    (SLEN*BSZ)            // 8192
#define NQKVB    (NHEAD*(3*D_HEAD+1))  // 3088
#define EPSV     1e-5f
#define SCALEV   0.125f                // 1/sqrt(64)

typedef short bf16x8 __attribute__((ext_vector_type(8)));
typedef float f32x4  __attribute__((ext_vector_type(4)));

__device__ __forceinline__ unsigned short f2bf(float f){
  unsigned int u = __float_as_uint(f);
  u = (u + 0x7fffu + ((u >> 16) & 1u)) >> 16;   // RNE
  return (unsigned short)u;
}
__device__ __forceinline__ float bf2f(unsigned short s){
  return __uint_as_float(((unsigned int)s) << 16);
}

// ------------------------------------------------------------------ cast
__global__ void cast_bf16_kernel(const float* __restrict__ src,
                                 unsigned short* __restrict__ dst, int n4){
  int stride = gridDim.x * blockDim.x;
  for (int i = blockIdx.x*blockDim.x + threadIdx.x; i < n4; i += stride){
    float4 f = ((const float4*)src)[i];
    ushort4 u;
    u.x = f2bf(f.x); u.y = f2bf(f.y); u.z = f2bf(f.z); u.w = f2bf(f.w);
    ((ushort4*)dst)[i] = u;
  }
}

// ------------------------------------------------------------------ GEMM (NT)
// C[m][n] = sum_k A[m][k]*B[n][k];  A: MxK bf16 row-major, B: NxK bf16 row-major.
// Block tile 128(M) x 64(N), BK=32. 4 waves; wave w owns 16 n-columns.
template<bool OUT_BF16>
__global__ __launch_bounds__(256) void gemm_nt_kernel(
    const unsigned short* __restrict__ A, const unsigned short* __restrict__ B,
    void* __restrict__ C, int M, int N, int K){
  const int LDT = 40;                       // lds row stride (bf16), 80B: 16B-aligned, 2-way banks
  __shared__ __align__(16) unsigned short sA[128*LDT];
  __shared__ __align__(16) unsigned short sB[64*LDT];
  int m0 = blockIdx.x * 128, n0 = blockIdx.y * 64;
  int tid = threadIdx.x;
  int wv = tid >> 6, ln = tid & 63;
  int lm = ln & 15, quad = ln >> 4;
  f32x4 acc[8] = {};

  for (int kt = 0; kt < K; kt += 32){
    __syncthreads();
    // stage A: 128 rows x 32 k = 512 segments of 8 bf16
    #pragma unroll
    for (int s = tid; s < 512; s += 256){
      int row = s >> 2, seg = s & 3;
      uint4 d = *(const uint4*)(A + (size_t)(m0+row)*K + kt + seg*8);
      *(uint4*)(&sA[row*LDT + seg*8]) = d;
    }
    // stage B: 64 rows x 32 k = 256 segments
    {
      int row = tid >> 2, seg = tid & 3;
      uint4 d = make_uint4(0u,0u,0u,0u);
      if (n0 + row < N)
        d = *(const uint4*)(B + (size_t)(n0+row)*K + kt + seg*8);
      *(uint4*)(&sB[row*LDT + seg*8]) = d;
    }
    __syncthreads();
    bf16x8 bfrag = *(const bf16x8*)(&sB[(wv*16 + lm)*LDT + quad*8]);
    #pragma unroll
    for (int mt = 0; mt < 8; ++mt){
      bf16x8 afrag = *(const bf16x8*)(&sA[(mt*16 + lm)*LDT + quad*8]);
      acc[mt] = __builtin_amdgcn_mfma_f32_16x16x32_bf16(afrag, bfrag, acc[mt], 0, 0, 0);
    }
  }

  int col = n0 + wv*16 + lm;
  if (col < N){
    #pragma unroll
    for (int mt = 0; mt < 8; ++mt){
      int rowm = m0 + mt*16 + quad*4;
      size_t cb = (size_t)rowm * N + col;
      #pragma unroll
      for (int rr = 0; rr < 4; ++rr){
        float v = acc[mt][rr];
        if (OUT_BF16) ((unsigned short*)C)[cb + (size_t)rr*N] = f2bf(v);
        else          ((float*)C)[cb + (size_t)rr*N] = v;
      }
    }
  }
}

// ------------------------------------------------------------------ preprocess
// one wave per (row m = t*4+b, head h): elu+1, normalize q,k; sigmoid(beta).
__global__ __launch_bounds__(256) void prep_kernel(
    const unsigned short* __restrict__ qkvb,
    float* __restrict__ qb, float* __restrict__ kb, float* __restrict__ vb,
    float4* __restrict__ scal){
  int gid = blockIdx.x*4 + (threadIdx.x >> 6);   // m*16 + h, 0..131071
  int ln  = threadIdx.x & 63;
  int m = gid >> 4, h = gid & 15;
  size_t rb = (size_t)m * NQKVB + (size_t)h * 193;
  float qr = bf2f(qkvb[rb + ln]);
  float kr = bf2f(qkvb[rb + 64 + ln]);
  float vr = bf2f(qkvb[rb + 128 + ln]);
  float br = bf2f(qkvb[rb + 192]);
  float q1 = qr > 0.f ? qr + 1.f : __expf(qr);   // elu(x)+1
  float k1 = kr > 0.f ? kr + 1.f : __expf(kr);
  float sq = q1, sk = k1;
  #pragma unroll
  for (int off = 1; off < 64; off <<= 1){
    sq += __shfl_xor(sq, off, 64);
    sk += __shfl_xor(sk, off, 64);
  }
  float qn = q1 / sq, kn = k1 / sk;
  int b = m & 3, t = m >> 2;
  int bh = b*16 + h;
  size_t o = ((size_t)bh*SLEN + t)*64 + ln;
  qb[o] = qn; kb[o] = kn; vb[o] = vr;
  if (ln == 0){
    float sb = 1.f / (1.f + __expf(-br));
    scal[(size_t)bh*SLEN + t] = make_float4(0.f, 0.f, 0.f, sb);
  }
}

// ------------------------------------------------------------------ cumsum over l
__global__ __launch_bounds__(64) void cumsum_kernel(
    const float* __restrict__ kb, float* __restrict__ Ab){
  int bh = blockIdx.x, ln = threadIdx.x;
  size_t base = (size_t)bh*SLEN*64 + ln;
  float acc = 0.f;
  #pragma unroll 4
  for (int t = 0; t < SLEN; ++t){
    acc += kb[base + (size_t)t*64];
    Ab[base + (size_t)t*64] = acc;
  }
}

// ------------------------------------------------------------------ denominators
// per (bh,t): key_denom=<acc_{t-1},kn> (t=0 -> 1), denominator=<acc_t,qn>,
// kf = kn/(kd+eps) (in place), scal = {beta*kd, <kf,qn>, 1/(den+eps), -}
__global__ __launch_bounds__(256) void kden_kernel(
    const float* __restrict__ Ab, float* __restrict__ kb,
    const float* __restrict__ qb, float4* __restrict__ scal){
  int gid = blockIdx.x*4 + (threadIdx.x >> 6);   // bh*2048 + t
  int ln  = threadIdx.x & 63;
  int t = gid & (SLEN-1);
  size_t o = (size_t)gid*64 + ln;
  float a = Ab[o], kn = kb[o], qn = qb[o];
  float d0 = (a - kn)*kn, d1 = a*qn, d2 = kn*qn;
  #pragma unroll
  for (int off = 1; off < 64; off <<= 1){
    d0 += __shfl_xor(d0, off, 64);
    d1 += __shfl_xor(d1, off, 64);
    d2 += __shfl_xor(d2, off, 64);
  }
  float kd  = (t == 0) ? 1.f : d0;
  float inv = 1.f / (kd + EPSV);
  kb[o] = kn * inv;
  if (ln == 0){
    float4 s = scal[gid];
    scal[gid] = make_float4(s.w * kd, d2 * inv, 1.f/(d1 + EPSV), 0.f);
  }
}

// ------------------------------------------------------------------ delta-rule recurrence
// grid (64 bh, 4 row-groups), 64 threads. lane: row r = grp*16 + (ln>>2),
// quarter c = ln&3 owns W[r][c*16 .. c*16+16). No LDS, no barriers.
#define DOT4(a,b) ((a).x*(b).x + (a).y*(b).y + (a).z*(b).z + (a).w*(b).w)
#define FMA4(W,d,k) { (W).x += (d)*(k).x; (W).y += (d)*(k).y; (W).z += (d)*(k).z; (W).w += (d)*(k).w; }

__global__ __launch_bounds__(64) void recur_kernel(
    const float* __restrict__ kb, const float* __restrict__ qb,
    const float* __restrict__ vb, const float4* __restrict__ scal,
    unsigned short* __restrict__ lo){
  int bh = blockIdx.x;
  int grp = blockIdx.y;
  int ln = threadIdx.x;
  int r = grp*16 + (ln >> 2);
  int c = ln & 3;
  int bb = bh >> 4, hh = bh & 15;
  size_t base = (size_t)bh * SLEN * 64;
  const float4* k4 = (const float4*)(kb + base);
  const float4* q4 = (const float4*)(qb + base);
  const float*  vv = vb + base + r;
  const float4* sc4 = scal + (size_t)bh * SLEN;
  unsigned short* lop = lo + (size_t)bb*DMODEL + (size_t)hh*64 + r;

  float4 W0 = {0,0,0,0}, W1 = {0,0,0,0}, W2 = {0,0,0,0}, W3 = {0,0,0,0};
  int fb = c*4;
  #pragma unroll 2
  for (int t = 0; t < SLEN; ++t){
    int tb = t*16 + fb;
    float4 ka = k4[tb+0], kbv = k4[tb+1], kc = k4[tb+2], kd = k4[tb+3];
    float4 qa = q4[tb+0], qbv = q4[tb+1], qc = q4[tb+2], qd = q4[tb+3];
    float vr = vv[(size_t)t*64];
    float4 sc = sc4[t];
    float vo = DOT4(W0,ka) + DOT4(W1,kbv) + DOT4(W2,kc) + DOT4(W3,kd);
    float p  = DOT4(W0,qa) + DOT4(W1,qbv) + DOT4(W2,qc) + DOT4(W3,qd);
    vo += __shfl_xor(vo, 1, 64); vo += __shfl_xor(vo, 2, 64);
    p  += __shfl_xor(p , 1, 64); p  += __shfl_xor(p , 2, 64);
    float delta = sc.x * (vr - vo);
    FMA4(W0, delta, ka); FMA4(W1, delta, kbv); FMA4(W2, delta, kc); FMA4(W3, delta, kd);
    if (c == 0){
      float ov = (p + delta*sc.y) * sc.z * SCALEV;
      lop[(size_t)t*(BSZ*DMODEL)] = f2bf(ov);
    }
  }
}

// ------------------------------------------------------------------ residual + layernorm
__global__ __launch_bounds__(256) void ln_kernel(
    const float* __restrict__ hin, const float* __restrict__ attn,
    const float* __restrict__ g, const float* __restrict__ bta,
    float* __restrict__ out){
  int row = blockIdx.x, tid = threadIdx.x;
  size_t rb = (size_t)row * DMODEL;
  float4 hv = ((const float4*)(hin + rb))[tid];
  float4 av = ((const float4*)(attn + rb))[tid];
  float4 x;
  x.x = hv.x + av.x; x.y = hv.y + av.y; x.z = hv.z + av.z; x.w = hv.w + av.w;
  float s  = x.x + x.y + x.z + x.w;
  float ss = x.x*x.x + x.y*x.y + x.z*x.z + x.w*x.w;
  #pragma unroll
  for (int off = 1; off < 64; off <<= 1){
    s  += __shfl_xor(s , off, 64);
    ss += __shfl_xor(ss, off, 64);
  }
  __shared__ float ls[4], lq[4];
  int wv = tid >> 6, ln = tid & 63;
  if (ln == 0){ ls[wv] = s; lq[wv] = ss; }
  __syncthreads();
  s  = ls[0] + ls[1] + ls[2] + ls[3];
  ss = lq[0] + lq[1] + lq[2] + lq[3];
  float mu  = s * (1.f/DMODEL);
  float var = ss * (1.f/DMODEL) - mu*mu;
  float rstd = rsqrtf(var + EPSV);
  float4 gv = ((const float4*)g)[tid], bv = ((const float4*)bta)[tid];
  float4 o;
  o.x = (x.x-mu)*rstd*gv.x + bv.x;
  o.y = (x.y-mu)*rstd*gv.y + bv.y;
  o.z = (x.z-mu)*rstd*gv.z + bv.z;
  o.w = (x.w-mu)*rstd*gv.w + bv.w;
  ((float4*)(out + rb))[tid] = o;
}

// ------------------------------------------------------------------ launch
extern "C" void kernel_launch(void* const* d_in, const int* in_sizes, int n_in,
                              void* d_out, int out_size, void* d_ws, size_t ws_size,
                              hipStream_t stream){
  const float* h     = (const float*)d_in[0];
  const float* wqkvb = (const float*)d_in[1];
  const float* wo    = (const float*)d_in[2];
  const float* lng   = (const float*)d_in[3];
  const float* lnb   = (const float*)d_in[4];
  float* out = (float*)d_out;

  char* w = (char*)d_ws;
  auto take = [&](size_t bytes)->char*{
    char* p = w; w += (bytes + 255) & ~(size_t)255; return p;
  };
  unsigned short* h_bf    = (unsigned short*)take((size_t)MROWS*DMODEL*2);
  unsigned short* wq_bf   = (unsigned short*)take((size_t)NQKVB*DMODEL*2);
  unsigned short* wo_bf   = (unsigned short*)take((size_t)DMODEL*DMODEL*2);
  unsigned short* qkvb_bf = (unsigned short*)take((size_t)MROWS*NQKVB*2);
  float* qb   = (float*)take((size_t)MROWS*DMODEL*4);
  float* kb   = (float*)take((size_t)MROWS*DMODEL*4);
  float* vb   = (float*)take((size_t)MROWS*DMODEL*4);
  float* Ab   = (float*)take((size_t)MROWS*DMODEL*4);   // reused as attn after kden
  float4* scal = (float4*)take((size_t)64*SLEN*16);
  unsigned short* lo_bf = (unsigned short*)take((size_t)MROWS*DMODEL*2);
  float* attn = Ab;  // safe alias: Ab consumed by kden before gemm2 writes attn

  cast_bf16_kernel<<<2048, 256, 0, stream>>>(h,     h_bf,  MROWS*DMODEL/4);
  cast_bf16_kernel<<<1024, 256, 0, stream>>>(wqkvb, wq_bf, NQKVB*DMODEL/4);
  cast_bf16_kernel<<<512,  256, 0, stream>>>(wo,    wo_bf, DMODEL*DMODEL/4);

  gemm_nt_kernel<true><<<dim3(MROWS/128, (NQKVB+63)/64), 256, 0, stream>>>(
      h_bf, wq_bf, qkvb_bf, MROWS, NQKVB, DMODEL);

  prep_kernel<<<MROWS*NHEAD/4, 256, 0, stream>>>(qkvb_bf, qb, kb, vb, scal);
  cumsum_kernel<<<64, 64, 0, stream>>>(kb, Ab);
  kden_kernel<<<64*SLEN/4, 256, 0, stream>>>(Ab, kb, qb, scal);
  recur_kernel<<<dim3(64, 4), 64, 0, stream>>>(kb, qb, vb, scal, lo_bf);

  gemm_nt_kernel<false><<<dim3(MROWS/128, DMODEL/64), 256, 0, stream>>>(
      lo_bf, wo_bf, attn, MROWS, DMODEL, DMODEL);

  ln_kernel<<<MROWS, 256, 0, stream>>>(h, attn, lng, lnb, out);
  (void)in_sizes; (void)n_in; (void)out_size; (void)ws_size;
}

// Round 2
// 860.635 us; speedup vs baseline: 2.3206x; 2.3206x over previous
//
#include <hip/hip_runtime.h>
#include <cstdint>
#include <cstddef>

#define D_HEAD   64
#define NHEAD    16
#define DMODEL   1024
#define SLEN     2048
#define BSZ      4
#define MROWS    (SLEN*BSZ)            // 8192
#define NQKVB    (NHEAD*(3*D_HEAD+1))  // 3088
#define EPSV     1e-5f
#define SCALEV   0.125f                // 1/sqrt(64)

typedef short bf16x8 __attribute__((ext_vector_type(8)));
typedef float f32x4  __attribute__((ext_vector_type(4)));

__device__ __forceinline__ unsigned short f2bf(float f){
  unsigned int u = __float_as_uint(f);
  u = (u + 0x7fffu + ((u >> 16) & 1u)) >> 16;   // RNE
  return (unsigned short)u;
}
__device__ __forceinline__ float bf2f(unsigned short s){
  return __uint_as_float(((unsigned int)s) << 16);
}

// ------------------------------------------------------------------ cast
__global__ void cast_bf16_kernel(const float* __restrict__ src,
                                 unsigned short* __restrict__ dst, int n4){
  int stride = gridDim.x * blockDim.x;
  for (int i = blockIdx.x*blockDim.x + threadIdx.x; i < n4; i += stride){
    float4 f = ((const float4*)src)[i];
    ushort4 u;
    u.x = f2bf(f.x); u.y = f2bf(f.y); u.z = f2bf(f.z); u.w = f2bf(f.w);
    ((ushort4*)dst)[i] = u;
  }
}

// ------------------------------------------------------------------ GEMM (NT)
// C[m][n] = sum_k A[m][k]*B[n][k];  A: MxK bf16 row-major, B: NxK bf16 row-major.
// Block tile 128(M) x 64(N), BK=32. 4 waves; wave w owns 16 n-columns.
template<bool OUT_BF16>
__global__ __launch_bounds__(256) void gemm_nt_kernel(
    const unsigned short* __restrict__ A, const unsigned short* __restrict__ B,
    void* __restrict__ C, int M, int N, int K){
  const int LDT = 40;                       // lds row stride (bf16), 80B: 16B-aligned, 2-way banks
  __shared__ __align__(16) unsigned short sA[128*LDT];
  __shared__ __align__(16) unsigned short sB[64*LDT];
  int m0 = blockIdx.x * 128, n0 = blockIdx.y * 64;
  int tid = threadIdx.x;
  int wv = tid >> 6, ln = tid & 63;
  int lm = ln & 15, quad = ln >> 4;
  f32x4 acc[8] = {};

  for (int kt = 0; kt < K; kt += 32){
    __syncthreads();
    // stage A: 128 rows x 32 k = 512 segments of 8 bf16
    #pragma unroll
    for (int s = tid; s < 512; s += 256){
      int row = s >> 2, seg = s & 3;
      uint4 d = *(const uint4*)(A + (size_t)(m0+row)*K + kt + seg*8);
      *(uint4*)(&sA[row*LDT + seg*8]) = d;
    }
    // stage B: 64 rows x 32 k = 256 segments
    {
      int row = tid >> 2, seg = tid & 3;
      uint4 d = make_uint4(0u,0u,0u,0u);
      if (n0 + row < N)
        d = *(const uint4*)(B + (size_t)(n0+row)*K + kt + seg*8);
      *(uint4*)(&sB[row*LDT + seg*8]) = d;
    }
    __syncthreads();
    bf16x8 bfrag = *(const bf16x8*)(&sB[(wv*16 + lm)*LDT + quad*8]);
    #pragma unroll
    for (int mt = 0; mt < 8; ++mt){
      bf16x8 afrag = *(const bf16x8*)(&sA[(mt*16 + lm)*LDT + quad*8]);
      acc[mt] = __builtin_amdgcn_mfma_f32_16x16x32_bf16(afrag, bfrag, acc[mt], 0, 0, 0);
    }
  }

  int col = n0 + wv*16 + lm;
  if (col < N){
    #pragma unroll
    for (int mt = 0; mt < 8; ++mt){
      int rowm = m0 + mt*16 + quad*4;
      size_t cb = (size_t)rowm * N + col;
      #pragma unroll
      for (int rr = 0; rr < 4; ++rr){
        float v = acc[mt][rr];
        if (OUT_BF16) ((unsigned short*)C)[cb + (size_t)rr*N] = f2bf(v);
        else          ((float*)C)[cb + (size_t)rr*N] = v;
      }
    }
  }
}

// ------------------------------------------------------------------ preprocess
// one wave per (row m = t*4+b, head h): elu+1, normalize q,k; sigmoid(beta).
__global__ __launch_bounds__(256) void prep_kernel(
    const unsigned short* __restrict__ qkvb,
    float* __restrict__ qb, float* __restrict__ kb, float* __restrict__ vb,
    float4* __restrict__ scal){
  int gid = blockIdx.x*4 + (threadIdx.x >> 6);   // m*16 + h, 0..131071
  int ln  = threadIdx.x & 63;
  int m = gid >> 4, h = gid & 15;
  size_t rb = (size_t)m * NQKVB + (size_t)h * 193;
  float qr = bf2f(qkvb[rb + ln]);
  float kr = bf2f(qkvb[rb + 64 + ln]);
  float vr = bf2f(qkvb[rb + 128 + ln]);
  float br = bf2f(qkvb[rb + 192]);
  float q1 = qr > 0.f ? qr + 1.f : __expf(qr);   // elu(x)+1
  float k1 = kr > 0.f ? kr + 1.f : __expf(kr);
  float sq = q1, sk = k1;
  #pragma unroll
  for (int off = 1; off < 64; off <<= 1){
    sq += __shfl_xor(sq, off, 64);
    sk += __shfl_xor(sk, off, 64);
  }
  float qn = q1 / sq, kn = k1 / sk;
  int b = m & 3, t = m >> 2;
  int bh = b*16 + h;
  size_t o = ((size_t)bh*SLEN + t)*64 + ln;
  qb[o] = qn; kb[o] = kn; vb[o] = vr;
  if (ln == 0){
    float sb = 1.f / (1.f + __expf(-br));
    scal[(size_t)bh*SLEN + t] = make_float4(0.f, 0.f, 0.f, sb);
  }
}

// ------------------------------------------------------------------ cumsum over l
__global__ __launch_bounds__(64) void cumsum_kernel(
    const float* __restrict__ kb, float* __restrict__ Ab){
  int bh = blockIdx.x, ln = threadIdx.x;
  size_t base = (size_t)bh*SLEN*64 + ln;
  float acc = 0.f;
  #pragma unroll 4
  for (int t = 0; t < SLEN; ++t){
    acc += kb[base + (size_t)t*64];
    Ab[base + (size_t)t*64] = acc;
  }
}

// ------------------------------------------------------------------ denominators
// per (bh,t): key_denom=<acc_{t-1},kn> (t=0 -> 1), denominator=<acc_t,qn>,
// kf = kn/(kd+eps) (in place), scal = {beta*kd, <kf,qn>, 1/(den+eps), -}
__global__ __launch_bounds__(256) void kden_kernel(
    const float* __restrict__ Ab, float* __restrict__ kb,
    const float* __restrict__ qb, float4* __restrict__ scal){
  int gid = blockIdx.x*4 + (threadIdx.x >> 6);   // bh*2048 + t
  int ln  = threadIdx.x & 63;
  int t = gid & (SLEN-1);
  size_t o = (size_t)gid*64 + ln;
  float a = Ab[o], kn = kb[o], qn = qb[o];
  float d0 = (a - kn)*kn, d1 = a*qn, d2 = kn*qn;
  #pragma unroll
  for (int off = 1; off < 64; off <<= 1){
    d0 += __shfl_xor(d0, off, 64);
    d1 += __shfl_xor(d1, off, 64);
    d2 += __shfl_xor(d2, off, 64);
  }
  float kd  = (t == 0) ? 1.f : d0;
  float inv = 1.f / (kd + EPSV);
  kb[o] = kn * inv;
  if (ln == 0){
    float4 s = scal[gid];
    scal[gid] = make_float4(s.w * kd, d2 * inv, 1.f/(d1 + EPSV), 0.f);
  }
}

// ------------------------------------------------------------------ delta-rule recurrence
// grid (64 bh, 4 row-groups), 64 threads. lane: row r = grp*16 + (ln>>2),
// quarter c = ln&3 owns W[r][c*16 .. c*16+16). 4-slot register prefetch
// (distance 3) hides L2 latency; DPP quad_perm reductions (lanes of one r
// are a hardware quad) keep the reduce at VALU latency.
#define DOT4(a,b) ((a).x*(b).x + (a).y*(b).y + (a).z*(b).z + (a).w*(b).w)
#define FMA4(W,d,k) { (W).x += (d)*(k).x; (W).y += (d)*(k).y; (W).z += (d)*(k).z; (W).w += (d)*(k).w; }

__device__ __forceinline__ float quad_sum(float x){
  // sum across the 4 lanes of a quad via DPP quad_perm (VALU-latency)
  float a = __int_as_float(__builtin_amdgcn_mov_dpp(__float_as_int(x), 0xB1, 0xF, 0xF, true)); // [1,0,3,2]
  float s = x + a;
  float b = __int_as_float(__builtin_amdgcn_mov_dpp(__float_as_int(s), 0x4E, 0xF, 0xF, true)); // [2,3,0,1]
  return s + b;
}

__global__ __launch_bounds__(64) void recur_kernel(
    const float* __restrict__ kb, const float* __restrict__ qb,
    const float* __restrict__ vb, const float4* __restrict__ scal,
    unsigned short* __restrict__ lo){
  int bh = blockIdx.x;
  int grp = blockIdx.y;
  int ln = threadIdx.x;
  int r = grp*16 + (ln >> 2);
  int c = ln & 3;
  int bb = bh >> 4, hh = bh & 15;
  size_t base = (size_t)bh * SLEN * 64;
  const float4* k4 = (const float4*)(kb + base);
  const float4* q4 = (const float4*)(qb + base);
  const float*  vv = vb + base + r;
  const float4* sc4 = scal + (size_t)bh * SLEN;
  unsigned short* lop = lo + (size_t)bb*DMODEL + (size_t)hh*64 + r;

  float4 W0 = {0,0,0,0}, W1 = {0,0,0,0}, W2 = {0,0,0,0}, W3 = {0,0,0,0};
  int fb = c*4;

  float4 kbuf[4][4], qbuf[4][4];
  float  vbuf[4];
  float4 sbuf[4];

  auto prefetch = [&](int t, int slot){
    int tc = t < SLEN ? t : SLEN-1;
    int tb = tc*16 + fb;
    #pragma unroll
    for (int i = 0; i < 4; ++i){
      kbuf[slot][i] = k4[tb+i];
      qbuf[slot][i] = q4[tb+i];
    }
    vbuf[slot] = vv[(size_t)tc*64];
    sbuf[slot] = sc4[tc];
  };

  prefetch(0, 0); prefetch(1, 1); prefetch(2, 2);

  for (int t0 = 0; t0 < SLEN; t0 += 4){
    #pragma unroll
    for (int u = 0; u < 4; ++u){
      int t = t0 + u;
      // issue loads for t+3 (into the slot freed 1 iter ago) BEFORE compute
      prefetch(t + 3, (u + 3) & 3);

      float4 ka = kbuf[u][0], kbv = kbuf[u][1], kc = kbuf[u][2], kd = kbuf[u][3];
      float4 qa = qbuf[u][0], qbv = qbuf[u][1], qc = qbuf[u][2], qd = qbuf[u][3];
      float vr = vbuf[u];
      float4 sc = sbuf[u];

      float vo = (DOT4(W0,ka) + DOT4(W1,kbv)) + (DOT4(W2,kc) + DOT4(W3,kd));
      float p  = (DOT4(W0,qa) + DOT4(W1,qbv)) + (DOT4(W2,qc) + DOT4(W3,qd));
      vo = quad_sum(vo);
      p  = quad_sum(p);
      float delta = sc.x * (vr - vo);
      FMA4(W0, delta, ka); FMA4(W1, delta, kbv); FMA4(W2, delta, kc); FMA4(W3, delta, kd);
      if (c == 0){
        float ov = (p + delta*sc.y) * sc.z * SCALEV;
        lop[(size_t)t*(BSZ*DMODEL)] = f2bf(ov);
      }
    }
  }
}

// ------------------------------------------------------------------ residual + layernorm
__global__ __launch_bounds__(256) void ln_kernel(
    const float* __restrict__ hin, const float* __restrict__ attn,
    const float* __restrict__ g, const float* __restrict__ bta,
    float* __restrict__ out){
  int row = blockIdx.x, tid = threadIdx.x;
  size_t rb = (size_t)row * DMODEL;
  float4 hv = ((const float4*)(hin + rb))[tid];
  float4 av = ((const float4*)(attn + rb))[tid];
  float4 x;
  x.x = hv.x + av.x; x.y = hv.y + av.y; x.z = hv.z + av.z; x.w = hv.w + av.w;
  float s  = x.x + x.y + x.z + x.w;
  float ss = x.x*x.x + x.y*x.y + x.z*x.z + x.w*x.w;
  #pragma unroll
  for (int off = 1; off < 64; off <<= 1){
    s  += __shfl_xor(s , off, 64);
    ss += __shfl_xor(ss, off, 64);
  }
  __shared__ float ls[4], lq[4];
  int wv = tid >> 6, ln = tid & 63;
  if (ln == 0){ ls[wv] = s; lq[wv] = ss; }
  __syncthreads();
  s  = ls[0] + ls[1] + ls[2] + ls[3];
  ss = lq[0] + lq[1] + lq[2] + lq[3];
  float mu  = s * (1.f/DMODEL);
  float var = ss * (1.f/DMODEL) - mu*mu;
  float rstd = rsqrtf(var + EPSV);
  float4 gv = ((const float4*)g)[tid], bv = ((const float4*)bta)[tid];
  float4 o;
  o.x = (x.x-mu)*rstd*gv.x + bv.x;
  o.y = (x.y-mu)*rstd*gv.y + bv.y;
  o.z = (x.z-mu)*rstd*gv.z + bv.z;
  o.w = (x.w-mu)*rstd*gv.w + bv.w;
  ((float4*)(out + rb))[tid] = o;
}

// ------------------------------------------------------------------ launch
extern "C" void kernel_launch(void* const* d_in, const int* in_sizes, int n_in,
                              void* d_out, int out_size, void* d_ws, size_t ws_size,
                              hipStream_t stream){
  const float* h     = (const float*)d_in[0];
  const float* wqkvb = (const float*)d_in[1];
  const float* wo    = (const float*)d_in[2];
  const float* lng   = (const float*)d_in[3];
  const float* lnb   = (const float*)d_in[4];
  float* out = (float*)d_out;

  char* w = (char*)d_ws;
  auto take = [&](size_t bytes)->char*{
    char* p = w; w += (bytes + 255) & ~(size_t)255; return p;
  };
  unsigned short* h_bf    = (unsigned short*)take((size_t)MROWS*DMODEL*2);
  unsigned short* wq_bf   = (unsigned short*)take((size_t)NQKVB*DMODEL*2);
  unsigned short* wo_bf   = (unsigned short*)take((size_t)DMODEL*DMODEL*2);
  unsigned short* qkvb_bf = (unsigned short*)take((size_t)MROWS*NQKVB*2);
  float* qb   = (float*)take((size_t)MROWS*DMODEL*4);
  float* kb   = (float*)take((size_t)MROWS*DMODEL*4);
  float* vb   = (float*)take((size_t)MROWS*DMODEL*4);
  float* Ab   = (float*)take((size_t)MROWS*DMODEL*4);   // reused as attn after kden
  float4* scal = (float4*)take((size_t)64*SLEN*16);
  unsigned short* lo_bf = (unsigned short*)take((size_t)MROWS*DMODEL*2);
  float* attn = Ab;  // safe alias: Ab consumed by kden before gemm2 writes attn

  cast_bf16_kernel<<<2048, 256, 0, stream>>>(h,     h_bf,  MROWS*DMODEL/4);
  cast_bf16_kernel<<<1024, 256, 0, stream>>>(wqkvb, wq_bf, NQKVB*DMODEL/4);
  cast_bf16_kernel<<<512,  256, 0, stream>>>(wo,    wo_bf, DMODEL*DMODEL/4);

  gemm_nt_kernel<true><<<dim3(MROWS/128, (NQKVB+63)/64), 256, 0, stream>>>(
      h_bf, wq_bf, qkvb_bf, MROWS, NQKVB, DMODEL);

  prep_kernel<<<MROWS*NHEAD/4, 256, 0, stream>>>(qkvb_bf, qb, kb, vb, scal);
  cumsum_kernel<<<64, 64, 0, stream>>>(kb, Ab);
  kden_kernel<<<64*SLEN/4, 256, 0, stream>>>(Ab, kb, qb, scal);
  recur_kernel<<<dim3(64, 4), 64, 0, stream>>>(kb, qb, vb, scal, lo_bf);

  gemm_nt_kernel<false><<<dim3(MROWS/128, DMODEL/64), 256, 0, stream>>>(
      lo_bf, wo_bf, attn, MROWS, DMODEL, DMODEL);

  ln_kernel<<<MROWS, 256, 0, stream>>>(h, attn, lng, lnb, out);
  (void)in_sizes; (void)n_in; (void)out_size; (void)ws_size;
}

// Round 4
// 724.511 us; speedup vs baseline: 2.7566x; 1.1879x over previous
//
#include <hip/hip_runtime.h>
#include <cstdint>
#include <cstddef>

#define D_HEAD   64
#define NHEAD    16
#define DMODEL   1024
#define SLEN     2048
#define BSZ      4
#define MROWS    (SLEN*BSZ)            // 8192
#define NQKVB    (NHEAD*(3*D_HEAD+1))  // 3088
#define EPSV     1e-5f
#define SCALEV   0.125f                // 1/sqrt(64)

typedef short bf16x8 __attribute__((ext_vector_type(8)));
typedef float f32x4  __attribute__((ext_vector_type(4)));

__device__ __forceinline__ unsigned short f2bf(float f){
  unsigned int u = __float_as_uint(f);
  u = (u + 0x7fffu + ((u >> 16) & 1u)) >> 16;   // RNE
  return (unsigned short)u;
}
__device__ __forceinline__ float bf2f(unsigned short s){
  return __uint_as_float(((unsigned int)s) << 16);
}

// ------------------------------------------------------------------ cast
__global__ void cast_bf16_kernel(const float* __restrict__ src,
                                 unsigned short* __restrict__ dst, int n4){
  int stride = gridDim.x * blockDim.x;
  for (int i = blockIdx.x*blockDim.x + threadIdx.x; i < n4; i += stride){
    float4 f = ((const float4*)src)[i];
    ushort4 u;
    u.x = f2bf(f.x); u.y = f2bf(f.y); u.z = f2bf(f.z); u.w = f2bf(f.w);
    ((ushort4*)dst)[i] = u;
  }
}

// ------------------------------------------------------------------ GEMM (NT)
// C[m][n] = sum_k A[m][k]*B[n][k];  A: MxK bf16 row-major, B: NxK bf16 row-major.
// Block tile 128(M) x 64(N), BK=32. 4 waves; wave w owns 16 n-columns.
template<bool OUT_BF16>
__global__ __launch_bounds__(256) void gemm_nt_kernel(
    const unsigned short* __restrict__ A, const unsigned short* __restrict__ B,
    void* __restrict__ C, int M, int N, int K){
  const int LDT = 40;                       // lds row stride (bf16), 80B: 16B-aligned, 2-way banks
  __shared__ __align__(16) unsigned short sA[128*LDT];
  __shared__ __align__(16) unsigned short sB[64*LDT];
  int m0 = blockIdx.x * 128, n0 = blockIdx.y * 64;
  int tid = threadIdx.x;
  int wv = tid >> 6, ln = tid & 63;
  int lm = ln & 15, quad = ln >> 4;
  f32x4 acc[8] = {};

  for (int kt = 0; kt < K; kt += 32){
    __syncthreads();
    // stage A: 128 rows x 32 k = 512 segments of 8 bf16
    #pragma unroll
    for (int s = tid; s < 512; s += 256){
      int row = s >> 2, seg = s & 3;
      uint4 d = *(const uint4*)(A + (size_t)(m0+row)*K + kt + seg*8);
      *(uint4*)(&sA[row*LDT + seg*8]) = d;
    }
    // stage B: 64 rows x 32 k = 256 segments
    {
      int row = tid >> 2, seg = tid & 3;
      uint4 d = make_uint4(0u,0u,0u,0u);
      if (n0 + row < N)
        d = *(const uint4*)(B + (size_t)(n0+row)*K + kt + seg*8);
      *(uint4*)(&sB[row*LDT + seg*8]) = d;
    }
    __syncthreads();
    bf16x8 bfrag = *(const bf16x8*)(&sB[(wv*16 + lm)*LDT + quad*8]);
    #pragma unroll
    for (int mt = 0; mt < 8; ++mt){
      bf16x8 afrag = *(const bf16x8*)(&sA[(mt*16 + lm)*LDT + quad*8]);
      acc[mt] = __builtin_amdgcn_mfma_f32_16x16x32_bf16(afrag, bfrag, acc[mt], 0, 0, 0);
    }
  }

  int col = n0 + wv*16 + lm;
  if (col < N){
    #pragma unroll
    for (int mt = 0; mt < 8; ++mt){
      int rowm = m0 + mt*16 + quad*4;
      size_t cb = (size_t)rowm * N + col;
      #pragma unroll
      for (int rr = 0; rr < 4; ++rr){
        float v = acc[mt][rr];
        if (OUT_BF16) ((unsigned short*)C)[cb + (size_t)rr*N] = f2bf(v);
        else          ((float*)C)[cb + (size_t)rr*N] = v;
      }
    }
  }
}

// ------------------------------------------------------------------ preprocess
// one wave per (row m = t*4+b, head h): elu+1, normalize q,k; sigmoid(beta).
__global__ __launch_bounds__(256) void prep_kernel(
    const unsigned short* __restrict__ qkvb,
    float* __restrict__ qb, float* __restrict__ kb, float* __restrict__ vb,
    float4* __restrict__ scal){
  int gid = blockIdx.x*4 + (threadIdx.x >> 6);   // m*16 + h, 0..131071
  int ln  = threadIdx.x & 63;
  int m = gid >> 4, h = gid & 15;
  size_t rb = (size_t)m * NQKVB + (size_t)h * 193;
  float qr = bf2f(qkvb[rb + ln]);
  float kr = bf2f(qkvb[rb + 64 + ln]);
  float vr = bf2f(qkvb[rb + 128 + ln]);
  float br = bf2f(qkvb[rb + 192]);
  float q1 = qr > 0.f ? qr + 1.f : __expf(qr);   // elu(x)+1
  float k1 = kr > 0.f ? kr + 1.f : __expf(kr);
  float sq = q1, sk = k1;
  #pragma unroll
  for (int off = 1; off < 64; off <<= 1){
    sq += __shfl_xor(sq, off, 64);
    sk += __shfl_xor(sk, off, 64);
  }
  float qn = q1 / sq, kn = k1 / sk;
  int b = m & 3, t = m >> 2;
  int bh = b*16 + h;
  size_t o = ((size_t)bh*SLEN + t)*64 + ln;
  qb[o] = qn; kb[o] = kn; vb[o] = vr;
  if (ln == 0){
    float sb = 1.f / (1.f + __expf(-br));
    scal[(size_t)bh*SLEN + t] = make_float4(0.f, 0.f, 0.f, sb);
  }
}

// ------------------------------------------------------------------ cumsum over l
__global__ __launch_bounds__(64) void cumsum_kernel(
    const float* __restrict__ kb, float* __restrict__ Ab){
  int bh = blockIdx.x, ln = threadIdx.x;
  size_t base = (size_t)bh*SLEN*64 + ln;
  float acc = 0.f;
  #pragma unroll 4
  for (int t = 0; t < SLEN; ++t){
    acc += kb[base + (size_t)t*64];
    Ab[base + (size_t)t*64] = acc;
  }
}

// ------------------------------------------------------------------ denominators
// per (bh,t): key_denom=<acc_{t-1},kn> (t=0 -> 1), denominator=<acc_t,qn>,
// kf = kn/(kd+eps) (in place), scal = {beta*kd, <kf,qn>, 1/(den+eps), -}
__global__ __launch_bounds__(256) void kden_kernel(
    const float* __restrict__ Ab, float* __restrict__ kb,
    const float* __restrict__ qb, float4* __restrict__ scal){
  int gid = blockIdx.x*4 + (threadIdx.x >> 6);   // bh*2048 + t
  int ln  = threadIdx.x & 63;
  int t = gid & (SLEN-1);
  size_t o = (size_t)gid*64 + ln;
  float a = Ab[o], kn = kb[o], qn = qb[o];
  float d0 = (a - kn)*kn, d1 = a*qn, d2 = kn*qn;
  #pragma unroll
  for (int off = 1; off < 64; off <<= 1){
    d0 += __shfl_xor(d0, off, 64);
    d1 += __shfl_xor(d1, off, 64);
    d2 += __shfl_xor(d2, off, 64);
  }
  float kd  = (t == 0) ? 1.f : d0;
  float inv = 1.f / (kd + EPSV);
  kb[o] = kn * inv;
  if (ln == 0){
    float4 s = scal[gid];
    scal[gid] = make_float4(s.w * kd, d2 * inv, 1.f/(d1 + EPSV), 0.f);
  }
}

// ------------------------------------------------------------------ delta-rule recurrence
// grid (64 bh, 16 row-groups), 64 threads = 4 rows x 16 col-groups.
// lane: r = grp*4 + (ln>>4), owns W[r][c*4..c*4+4), c = ln&15.
// 16-lane DPP rotate-allreduce; 8-slot register prefetch (distance 7).
#define DOT4(a,b) ((a).x*(b).x + (a).y*(b).y + (a).z*(b).z + (a).w*(b).w)

template<int CTRL>
__device__ __forceinline__ float dpp_add(float x){
  return x + __int_as_float(__builtin_amdgcn_mov_dpp(__float_as_int(x), CTRL, 0xF, 0xF, true));
}
__device__ __forceinline__ float red16(float x){
  x = dpp_add<0xB1>(x);    // quad_perm [1,0,3,2]  (xor 1)
  x = dpp_add<0x4E>(x);    // quad_perm [2,3,0,1]  (xor 2)
  x = dpp_add<0x124>(x);   // row_ror:4
  x = dpp_add<0x128>(x);   // row_ror:8
  return x;                // all 16 lanes of the row hold the row-sum
}

#define PD 8
__global__ __launch_bounds__(64) void recur_kernel(
    const float* __restrict__ kb, const float* __restrict__ qb,
    const float* __restrict__ vb, const float4* __restrict__ scal,
    unsigned short* __restrict__ lo){
  int bh = blockIdx.x;
  int grp = blockIdx.y;
  int ln = threadIdx.x;
  int c  = ln & 15;
  int r  = grp*4 + (ln >> 4);
  size_t base = (size_t)bh * SLEN * 64;
  const float4* kp = (const float4*)(kb + base) + c;   // +16 per t
  const float4* qp = (const float4*)(qb + base) + c;
  const float*  vp = vb + base + r;                    // +64 per t
  const float4* sp = scal + (size_t)bh * SLEN;         // +1 per t
  unsigned short* lop = lo + (size_t)(bh>>4)*DMODEL + (size_t)(bh&15)*64 + r;

  float4 W = {0,0,0,0};
  float4 kbuf[PD], qbuf[PD], sbuf[PD];
  float  vbuf[PD];

  #pragma unroll
  for (int s = 0; s < PD-1; ++s){
    kbuf[s] = kp[s*16];
    qbuf[s] = qp[s*16];
    vbuf[s] = vp[(size_t)s*64];
    sbuf[s] = sp[s];
  }

  for (int t0 = 0; t0 < SLEN; t0 += PD){
    #pragma unroll
    for (int u = 0; u < PD; ++u){
      int t = t0 + u;
      int ps = (u + PD - 1) & (PD - 1);
      int pt = t + PD - 1;                 // may run past SLEN into padding
      kbuf[ps] = kp[pt*16];
      qbuf[ps] = qp[pt*16];
      vbuf[ps] = vp[(size_t)pt*64];
      sbuf[ps] = sp[pt];

      float4 kv = kbuf[u], qv = qbuf[u], sc = sbuf[u];
      float vr = vbuf[u];
      float vo = red16(DOT4(W, kv));
      float p  = red16(DOT4(W, qv));
      float delta = sc.x * (vr - vo);
      W.x += delta*kv.x; W.y += delta*kv.y; W.z += delta*kv.z; W.w += delta*kv.w;
      if (c == 0){
        float ov = (p + delta*sc.y) * sc.z * SCALEV;
        lop[(size_t)t*(BSZ*DMODEL)] = f2bf(ov);
      }
    }
  }
}

// ------------------------------------------------------------------ residual + layernorm
__global__ __launch_bounds__(256) void ln_kernel(
    const float* __restrict__ hin, const float* __restrict__ attn,
    const float* __restrict__ g, const float* __restrict__ bta,
    float* __restrict__ out){
  int row = blockIdx.x, tid = threadIdx.x;
  size_t rb = (size_t)row * DMODEL;
  float4 hv = ((const float4*)(hin + rb))[tid];
  float4 av = ((const float4*)(attn + rb))[tid];
  float4 x;
  x.x = hv.x + av.x; x.y = hv.y + av.y; x.z = hv.z + av.z; x.w = hv.w + av.w;
  float s  = x.x + x.y + x.z + x.w;
  float ss = x.x*x.x + x.y*x.y + x.z*x.z + x.w*x.w;
  #pragma unroll
  for (int off = 1; off < 64; off <<= 1){
    s  += __shfl_xor(s , off, 64);
    ss += __shfl_xor(ss, off, 64);
  }
  __shared__ float ls[4], lq[4];
  int wv = tid >> 6, ln = tid & 63;
  if (ln == 0){ ls[wv] = s; lq[wv] = ss; }
  __syncthreads();
  s  = ls[0] + ls[1] + ls[2] + ls[3];
  ss = lq[0] + lq[1] + lq[2] + lq[3];
  float mu  = s * (1.f/DMODEL);
  float var = ss * (1.f/DMODEL) - mu*mu;
  float rstd = rsqrtf(var + EPSV);
  float4 gv = ((const float4*)g)[tid], bv = ((const float4*)bta)[tid];
  float4 o;
  o.x = (x.x-mu)*rstd*gv.x + bv.x;
  o.y = (x.y-mu)*rstd*gv.y + bv.y;
  o.z = (x.z-mu)*rstd*gv.z + bv.z;
  o.w = (x.w-mu)*rstd*gv.w + bv.w;
  ((float4*)(out + rb))[tid] = o;
}

// ------------------------------------------------------------------ launch
extern "C" void kernel_launch(void* const* d_in, const int* in_sizes, int n_in,
                              void* d_out, int out_size, void* d_ws, size_t ws_size,
                              hipStream_t stream){
  const float* h     = (const float*)d_in[0];
  const float* wqkvb = (const float*)d_in[1];
  const float* wo    = (const float*)d_in[2];
  const float* lng   = (const float*)d_in[3];
  const float* lnb   = (const float*)d_in[4];
  float* out = (float*)d_out;

  char* w = (char*)d_ws;
  auto take = [&](size_t bytes)->char*{
    char* p = w; w += (bytes + 255) & ~(size_t)255; return p;
  };
  unsigned short* h_bf    = (unsigned short*)take((size_t)MROWS*DMODEL*2);
  unsigned short* wq_bf   = (unsigned short*)take((size_t)NQKVB*DMODEL*2);
  unsigned short* wo_bf   = (unsigned short*)take((size_t)DMODEL*DMODEL*2);
  unsigned short* qkvb_bf = (unsigned short*)take((size_t)MROWS*NQKVB*2);
  float* qb   = (float*)take((size_t)MROWS*DMODEL*4 + 4096);  // +pad for prefetch overrun
  float* kb   = (float*)take((size_t)MROWS*DMODEL*4 + 4096);
  float* vb   = (float*)take((size_t)MROWS*DMODEL*4 + 4096);
  float* Ab   = (float*)take((size_t)MROWS*DMODEL*4);   // reused as attn after kden
  float4* scal = (float4*)take((size_t)64*SLEN*16 + 4096);
  unsigned short* lo_bf = (unsigned short*)take((size_t)MROWS*DMODEL*2);
  float* attn = Ab;  // safe alias: Ab consumed by kden before gemm2 writes attn

  cast_bf16_kernel<<<2048, 256, 0, stream>>>(h,     h_bf,  MROWS*DMODEL/4);
  cast_bf16_kernel<<<1024, 256, 0, stream>>>(wqkvb, wq_bf, NQKVB*DMODEL/4);
  cast_bf16_kernel<<<512,  256, 0, stream>>>(wo,    wo_bf, DMODEL*DMODEL/4);

  gemm_nt_kernel<true><<<dim3(MROWS/128, (NQKVB+63)/64), 256, 0, stream>>>(
      h_bf, wq_bf, qkvb_bf, MROWS, NQKVB, DMODEL);

  prep_kernel<<<MROWS*NHEAD/4, 256, 0, stream>>>(qkvb_bf, qb, kb, vb, scal);
  cumsum_kernel<<<64, 64, 0, stream>>>(kb, Ab);
  kden_kernel<<<64*SLEN/4, 256, 0, stream>>>(Ab, kb, qb, scal);
  recur_kernel<<<dim3(64, 16), 64, 0, stream>>>(kb, qb, vb, scal, lo_bf);

  gemm_nt_kernel<false><<<dim3(MROWS/128, DMODEL/64), 256, 0, stream>>>(
      lo_bf, wo_bf, attn, MROWS, DMODEL, DMODEL);

  ln_kernel<<<MROWS, 256, 0, stream>>>(h, attn, lng, lnb, out);
  (void)in_sizes; (void)n_in; (void)out_size; (void)ws_size;
}

// Round 5
// 585.185 us; speedup vs baseline: 3.4129x; 1.2381x over previous
//
#include <hip/hip_runtime.h>
#include <cstdint>
#include <cstddef>

#define D_HEAD   64
#define NHEAD    16
#define DMODEL   1024
#define SLEN     2048
#define BSZ      4
#define MROWS    (SLEN*BSZ)            // 8192
#define NQKVB    (NHEAD*(3*D_HEAD+1))  // 3088
#define NQPAD    3200                  // padded to 25*128 for the 128-tile GEMM
#define EPSV     1e-5f
#define SCALEV   0.125f                // 1/sqrt(64)

typedef short bf16x8 __attribute__((ext_vector_type(8)));
typedef float f32x4  __attribute__((ext_vector_type(4)));

__device__ __forceinline__ unsigned short f2bf(float f){
  unsigned int u = __float_as_uint(f);
  u = (u + 0x7fffu + ((u >> 16) & 1u)) >> 16;   // RNE
  return (unsigned short)u;
}
__device__ __forceinline__ float bf2f(unsigned short s){
  return __uint_as_float(((unsigned int)s) << 16);
}

__device__ __forceinline__ void gload_lds16(const unsigned short* g, unsigned short* l){
  __builtin_amdgcn_global_load_lds((const __attribute__((address_space(1))) void*)g,
                                   (__attribute__((address_space(3))) void*)l, 16, 0, 0);
}

// ------------------------------------------------------------------ cast
__global__ void cast_bf16_kernel(const float* __restrict__ src,
                                 unsigned short* __restrict__ dst, int n4){
  int stride = gridDim.x * blockDim.x;
  for (int i = blockIdx.x*blockDim.x + threadIdx.x; i < n4; i += stride){
    float4 f = ((const float4*)src)[i];
    ushort4 u;
    u.x = f2bf(f.x); u.y = f2bf(f.y); u.z = f2bf(f.z); u.w = f2bf(f.w);
    ((ushort4*)dst)[i] = u;
  }
}

// ------------------------------------------------------------------ GEMM (NT), m97 structure
// C[m][n] = sum_k A[m][k]*B[n][k]; A: MxK, B: NxK, bf16 row-major. 128x128 tile,
// BK=32, 4 waves (2x2 of 64x64), global_load_lds 16B staging, unpadded LDS.
// M,N,K must be multiples of 128/128/32 (N padded by caller; garbage cols unread).
template<bool OUT_BF16>
__global__ __launch_bounds__(256) void gemm_big_kernel(
    const unsigned short* __restrict__ A, const unsigned short* __restrict__ B,
    void* __restrict__ C, int M, int N, int K){
  __shared__ __align__(16) unsigned short sA[128*32];
  __shared__ __align__(16) unsigned short sB[128*32];
  int m0 = blockIdx.x * 128, n0 = blockIdx.y * 128;
  int tid = threadIdx.x;
  int wv = tid >> 6, ln = tid & 63;
  int lm = ln & 15, quad = ln >> 4;
  int wm = (wv >> 1) * 64, wn = (wv & 1) * 64;
  f32x4 acc[4][4] = {};

  for (int kt = 0; kt < K; kt += 32){
    __syncthreads();
    // stage A,B: 128 rows x 32 k each = 512 16B-segments; wave wv handles
    // segments [wv*128, wv*128+128): 2 issues of 64 lanes x 16B.
    #pragma unroll
    for (int it = 0; it < 2; ++it){
      int s = wv*128 + it*64 + ln;          // 0..511
      int row = s >> 2, sg = s & 3;
      gload_lds16(A + (size_t)(m0+row)*K + kt + sg*8, sA + (size_t)(wv*128 + it*64)*8);
      gload_lds16(B + (size_t)(n0+row)*K + kt + sg*8, sB + (size_t)(wv*128 + it*64)*8);
    }
    __syncthreads();
    bf16x8 af[4], bfr[4];
    #pragma unroll
    for (int i = 0; i < 4; ++i){
      af[i]  = *(const bf16x8*)(sA + ((wm + i*16 + lm)*32 + quad*8));
      bfr[i] = *(const bf16x8*)(sB + ((wn + i*16 + lm)*32 + quad*8));
    }
    #pragma unroll
    for (int mi = 0; mi < 4; ++mi)
      #pragma unroll
      for (int ni = 0; ni < 4; ++ni)
        acc[mi][ni] = __builtin_amdgcn_mfma_f32_16x16x32_bf16(af[mi], bfr[ni], acc[mi][ni], 0, 0, 0);
  }

  #pragma unroll
  for (int mi = 0; mi < 4; ++mi){
    int rowm = m0 + wm + mi*16 + quad*4;
    #pragma unroll
    for (int ni = 0; ni < 4; ++ni){
      int col = n0 + wn + ni*16 + lm;
      size_t cb = (size_t)rowm * N + col;
      #pragma unroll
      for (int rr = 0; rr < 4; ++rr){
        float v = acc[mi][ni][rr];
        if (OUT_BF16) ((unsigned short*)C)[cb + (size_t)rr*N] = f2bf(v);
        else          ((float*)C)[cb + (size_t)rr*N] = v;
      }
    }
  }
}

// ------------------------------------------------------------------ preprocess
// one wave per (row m = t*4+b, head h): elu+1, normalize q,k; sigmoid(beta).
__global__ __launch_bounds__(256) void prep_kernel(
    const unsigned short* __restrict__ qkvb,
    float* __restrict__ qb, float* __restrict__ kb, float* __restrict__ vb,
    float4* __restrict__ scal){
  int gid = blockIdx.x*4 + (threadIdx.x >> 6);   // m*16 + h
  int ln  = threadIdx.x & 63;
  int m = gid >> 4, h = gid & 15;
  size_t rb = (size_t)m * NQPAD + (size_t)h * 193;
  float qr = bf2f(qkvb[rb + ln]);
  float kr = bf2f(qkvb[rb + 64 + ln]);
  float vr = bf2f(qkvb[rb + 128 + ln]);
  float br = bf2f(qkvb[rb + 192]);
  float q1 = qr > 0.f ? qr + 1.f : __expf(qr);   // elu(x)+1
  float k1 = kr > 0.f ? kr + 1.f : __expf(kr);
  float sq = q1, sk = k1;
  #pragma unroll
  for (int off = 1; off < 64; off <<= 1){
    sq += __shfl_xor(sq, off, 64);
    sk += __shfl_xor(sk, off, 64);
  }
  float qn = q1 / sq, kn = k1 / sk;
  int b = m & 3, t = m >> 2;
  int bh = b*16 + h;
  size_t o = ((size_t)bh*SLEN + t)*64 + ln;
  qb[o] = qn; kb[o] = kn; vb[o] = vr;
  if (ln == 0){
    float sb = 1.f / (1.f + __expf(-br));
    scal[(size_t)bh*SLEN + t] = make_float4(0.f, 0.f, 0.f, sb);
  }
}

// ------------------------------------------------------------------ segmented cumsum over l
#define NSEG 16
#define SEGL (SLEN/NSEG)   // 128
__global__ __launch_bounds__(64) void segsum_kernel(
    const float* __restrict__ kb, float* __restrict__ S){
  int bh = blockIdx.x, seg = blockIdx.y, ln = threadIdx.x;
  size_t base = ((size_t)bh*SLEN + (size_t)seg*SEGL)*64 + ln;
  float s = 0.f;
  #pragma unroll 4
  for (int t = 0; t < SEGL; ++t) s += kb[base + (size_t)t*64];
  S[((size_t)bh*NSEG + seg)*64 + ln] = s;
}
__global__ __launch_bounds__(64) void scan_kernel(
    const float* __restrict__ kb, const float* __restrict__ S,
    float* __restrict__ Ab){
  int bh = blockIdx.x, seg = blockIdx.y, ln = threadIdx.x;
  float acc = 0.f;
  for (int s = 0; s < seg; ++s) acc += S[((size_t)bh*NSEG + s)*64 + ln];
  size_t base = ((size_t)bh*SLEN + (size_t)seg*SEGL)*64 + ln;
  #pragma unroll 4
  for (int t = 0; t < SEGL; ++t){
    acc += kb[base + (size_t)t*64];
    Ab[base + (size_t)t*64] = acc;
  }
}

// ------------------------------------------------------------------ denominators
__global__ __launch_bounds__(256) void kden_kernel(
    const float* __restrict__ Ab, float* __restrict__ kb,
    const float* __restrict__ qb, float4* __restrict__ scal){
  int gid = blockIdx.x*4 + (threadIdx.x >> 6);   // bh*2048 + t
  int ln  = threadIdx.x & 63;
  int t = gid & (SLEN-1);
  size_t o = (size_t)gid*64 + ln;
  float a = Ab[o], kn = kb[o], qn = qb[o];
  float d0 = (a - kn)*kn, d1 = a*qn, d2 = kn*qn;
  #pragma unroll
  for (int off = 1; off < 64; off <<= 1){
    d0 += __shfl_xor(d0, off, 64);
    d1 += __shfl_xor(d1, off, 64);
    d2 += __shfl_xor(d2, off, 64);
  }
  float kd  = (t == 0) ? 1.f : d0;
  float inv = 1.f / (kd + EPSV);
  kb[o] = kn * inv;
  if (ln == 0){
    float4 s = scal[gid];
    scal[gid] = make_float4(s.w * kd, d2 * inv, 1.f/(d1 + EPSV), 0.f);
  }
}

// ------------------------------------------------------------------ delta-rule recurrence
#define DOT4(a,b) ((a).x*(b).x + (a).y*(b).y + (a).z*(b).z + (a).w*(b).w)

template<int CTRL>
__device__ __forceinline__ float dpp_add(float x){
  return x + __int_as_float(__builtin_amdgcn_mov_dpp(__float_as_int(x), CTRL, 0xF, 0xF, true));
}
__device__ __forceinline__ float red16(float x){
  x = dpp_add<0xB1>(x);    // quad_perm [1,0,3,2]
  x = dpp_add<0x4E>(x);    // quad_perm [2,3,0,1]
  x = dpp_add<0x124>(x);   // row_ror:4
  x = dpp_add<0x128>(x);   // row_ror:8
  return x;
}

#define PD 8
__global__ __launch_bounds__(64) void recur_kernel(
    const float* __restrict__ kb, const float* __restrict__ qb,
    const float* __restrict__ vb, const float4* __restrict__ scal,
    unsigned short* __restrict__ lo){
  int bh = blockIdx.x;
  int grp = blockIdx.y;
  int ln = threadIdx.x;
  int c  = ln & 15;
  int r  = grp*4 + (ln >> 4);
  size_t base = (size_t)bh * SLEN * 64;
  const float4* kp = (const float4*)(kb + base) + c;
  const float4* qp = (const float4*)(qb + base) + c;
  const float*  vp = vb + base + r;
  const float4* sp = scal + (size_t)bh * SLEN;
  unsigned short* lop = lo + (size_t)(bh>>4)*DMODEL + (size_t)(bh&15)*64 + r;

  float4 W = {0,0,0,0};
  float4 kbuf[PD], qbuf[PD], sbuf[PD];
  float  vbuf[PD];

  #pragma unroll
  for (int s = 0; s < PD-1; ++s){
    kbuf[s] = kp[s*16];
    qbuf[s] = qp[s*16];
    vbuf[s] = vp[(size_t)s*64];
    sbuf[s] = sp[s];
  }

  for (int t0 = 0; t0 < SLEN; t0 += PD){
    #pragma unroll
    for (int u = 0; u < PD; ++u){
      int t = t0 + u;
      int ps = (u + PD - 1) & (PD - 1);
      int pt = t + PD - 1;                 // may run past SLEN into padding
      kbuf[ps] = kp[pt*16];
      qbuf[ps] = qp[pt*16];
      vbuf[ps] = vp[(size_t)pt*64];
      sbuf[ps] = sp[pt];

      float4 kv = kbuf[u], qv = qbuf[u], sc = sbuf[u];
      float vr = vbuf[u];
      float vo = red16(DOT4(W, kv));
      float p  = red16(DOT4(W, qv));
      float delta = sc.x * (vr - vo);
      W.x += delta*kv.x; W.y += delta*kv.y; W.z += delta*kv.z; W.w += delta*kv.w;
      if (c == 0){
        float ov = (p + delta*sc.y) * sc.z * SCALEV;
        lop[(size_t)t*(BSZ*DMODEL)] = f2bf(ov);
      }
    }
  }
}

// ------------------------------------------------------------------ residual + layernorm
__global__ __launch_bounds__(256) void ln_kernel(
    const float* __restrict__ hin, const float* __restrict__ attn,
    const float* __restrict__ g, const float* __restrict__ bta,
    float* __restrict__ out){
  int row = blockIdx.x, tid = threadIdx.x;
  size_t rb = (size_t)row * DMODEL;
  float4 hv = ((const float4*)(hin + rb))[tid];
  float4 av = ((const float4*)(attn + rb))[tid];
  float4 x;
  x.x = hv.x + av.x; x.y = hv.y + av.y; x.z = hv.z + av.z; x.w = hv.w + av.w;
  float s  = x.x + x.y + x.z + x.w;
  float ss = x.x*x.x + x.y*x.y + x.z*x.z + x.w*x.w;
  #pragma unroll
  for (int off = 1; off < 64; off <<= 1){
    s  += __shfl_xor(s , off, 64);
    ss += __shfl_xor(ss, off, 64);
  }
  __shared__ float ls[4], lq[4];
  int wv = tid >> 6, ln = tid & 63;
  if (ln == 0){ ls[wv] = s; lq[wv] = ss; }
  __syncthreads();
  s  = ls[0] + ls[1] + ls[2] + ls[3];
  ss = lq[0] + lq[1] + lq[2] + lq[3];
  float mu  = s * (1.f/DMODEL);
  float var = ss * (1.f/DMODEL) - mu*mu;
  float rstd = rsqrtf(var + EPSV);
  float4 gv = ((const float4*)g)[tid], bv = ((const float4*)bta)[tid];
  float4 o;
  o.x = (x.x-mu)*rstd*gv.x + bv.x;
  o.y = (x.y-mu)*rstd*gv.y + bv.y;
  o.z = (x.z-mu)*rstd*gv.z + bv.z;
  o.w = (x.w-mu)*rstd*gv.w + bv.w;
  ((float4*)(out + rb))[tid] = o;
}

// ------------------------------------------------------------------ launch
extern "C" void kernel_launch(void* const* d_in, const int* in_sizes, int n_in,
                              void* d_out, int out_size, void* d_ws, size_t ws_size,
                              hipStream_t stream){
  const float* h     = (const float*)d_in[0];
  const float* wqkvb = (const float*)d_in[1];
  const float* wo    = (const float*)d_in[2];
  const float* lng   = (const float*)d_in[3];
  const float* lnb   = (const float*)d_in[4];
  float* out = (float*)d_out;

  char* w = (char*)d_ws;
  auto take = [&](size_t bytes)->char*{
    char* p = w; w += (bytes + 255) & ~(size_t)255; return p;
  };
  unsigned short* h_bf    = (unsigned short*)take((size_t)MROWS*DMODEL*2);
  unsigned short* wq_bf   = (unsigned short*)take((size_t)NQPAD*DMODEL*2);   // padded rows
  unsigned short* wo_bf   = (unsigned short*)take((size_t)DMODEL*DMODEL*2);
  unsigned short* qkvb_bf = (unsigned short*)take((size_t)MROWS*NQPAD*2);    // padded cols
  float* qb   = (float*)take((size_t)MROWS*DMODEL*4 + 4096);  // +pad for prefetch overrun
  float* kb   = (float*)take((size_t)MROWS*DMODEL*4 + 4096);
  float* vb   = (float*)take((size_t)MROWS*DMODEL*4 + 4096);
  float* Ab   = (float*)take((size_t)MROWS*DMODEL*4);   // reused as attn after kden
  float4* scal = (float4*)take((size_t)64*SLEN*16 + 4096);
  unsigned short* lo_bf = (unsigned short*)take((size_t)MROWS*DMODEL*2);
  float* Sseg = (float*)take((size_t)64*NSEG*64*4);
  float* attn = Ab;  // safe alias: Ab consumed by kden before gemm2 writes attn

  cast_bf16_kernel<<<2048, 256, 0, stream>>>(h,     h_bf,  MROWS*DMODEL/4);
  cast_bf16_kernel<<<1024, 256, 0, stream>>>(wqkvb, wq_bf, NQKVB*DMODEL/4);
  cast_bf16_kernel<<<512,  256, 0, stream>>>(wo,    wo_bf, DMODEL*DMODEL/4);

  gemm_big_kernel<true><<<dim3(MROWS/128, NQPAD/128), 256, 0, stream>>>(
      h_bf, wq_bf, qkvb_bf, MROWS, NQPAD, DMODEL);

  prep_kernel<<<MROWS*NHEAD/4, 256, 0, stream>>>(qkvb_bf, qb, kb, vb, scal);
  segsum_kernel<<<dim3(64, NSEG), 64, 0, stream>>>(kb, Sseg);
  scan_kernel<<<dim3(64, NSEG), 64, 0, stream>>>(kb, Sseg, Ab);
  kden_kernel<<<64*SLEN/4, 256, 0, stream>>>(Ab, kb, qb, scal);
  recur_kernel<<<dim3(64, 16), 64, 0, stream>>>(kb, qb, vb, scal, lo_bf);

  gemm_big_kernel<false><<<dim3(MROWS/128, DMODEL/128), 256, 0, stream>>>(
      lo_bf, wo_bf, attn, MROWS, DMODEL, DMODEL);

  ln_kernel<<<MROWS, 256, 0, stream>>>(h, attn, lng, lnb, out);
  (void)in_sizes; (void)n_in; (void)out_size; (void)ws_size;
}